// Round 7
// baseline (96.954 us; speedup 1.0000x reference)
//
#include <hip/hip_runtime.h>

// MultiHeadSelfAttention: B=4 N=2048 F=512 H=8 D=64, scale = 1/sqrt(512)
// Pipeline: cvt x->f16, cvt W^T->f16, fused QKV GEMM (mfma f16, gload_lds
// staging, Q pre-scaled by log2e/sqrt(512), V stored TRANSPOSED [B][H][D][N]),
// flash attention (swapped QK^T + K-row permutation pi, no-max softmax,
// ones-MFMA denominators, 128-thr blocks for 4 blocks/CU), output GEMM
// (128x64 tiles, fp32+bias).
// ws: xb@0 | wt@8MB | Q@10MB K@18MB Vt@26MB | CTX@34MB.

typedef _Float16 f16;
typedef _Float16 f16x2 __attribute__((ext_vector_type(2)));
typedef _Float16 f16x4 __attribute__((ext_vector_type(4)));
typedef _Float16 f16x8 __attribute__((ext_vector_type(8)));
typedef float f32x4 __attribute__((ext_vector_type(4)));

#define MFMA16(a, b, c) __builtin_amdgcn_mfma_f32_16x16x32_f16((a), (b), (c), 0, 0, 0)
#if __has_builtin(__builtin_amdgcn_exp2f)
#define EXP2(x) __builtin_amdgcn_exp2f(x)
#else
#define EXP2(x) exp2f(x)
#endif
#define GLLDS16(gp, lp)                                                    \
  __builtin_amdgcn_global_load_lds(                                        \
      (const __attribute__((address_space(1))) unsigned int*)(gp),         \
      (__attribute__((address_space(3))) unsigned int*)(lp), 16, 0, 0)

// log2(e) / sqrt(512)
#define QSCALE 0.0637587f

// ---------------------------------------------------------------- cvt x -> f16
__global__ __launch_bounds__(256) void k_cvt_x(const float* __restrict__ x,
                                               f16* __restrict__ xb, int n4) {
  int i = blockIdx.x * 256 + threadIdx.x;
  const int stride = gridDim.x * 256;
  const float4* xp = (const float4*)x;
  f16x4* op = (f16x4*)xb;
  for (; i < n4; i += stride) {
    float4 v = xp[i];
    f16x4 o = {(f16)v.x, (f16)v.y, (f16)v.z, (f16)v.w};
    op[i] = o;
  }
}

// ------------------------------------------------- cvt weights -> W^T in f16
__global__ __launch_bounds__(256) void k_cvt_w(const float* __restrict__ Wq,
                                               const float* __restrict__ Wk,
                                               const float* __restrict__ Wv,
                                               const float* __restrict__ Wo,
                                               f16* __restrict__ wt) {
  const int w = blockIdx.y;
  const float* W = (w == 0) ? Wq : (w == 1) ? Wk : (w == 2) ? Wv : Wo;
  const int j0 = (blockIdx.x >> 4) * 32;
  const int k0 = (blockIdx.x & 15) * 32;
  __shared__ float tl[32][33];
  const int tx = threadIdx.x & 31, ty = threadIdx.x >> 5;
#pragma unroll
  for (int i = 0; i < 32; i += 8)
    tl[ty + i][tx] = W[(size_t)(k0 + ty + i) * 512 + j0 + tx];
  __syncthreads();
#pragma unroll
  for (int i = 0; i < 32; i += 8)
    wt[(size_t)w * 262144 + (size_t)(j0 + ty + i) * 512 + (k0 + tx)] =
        (f16)tl[tx][ty + i];
}

// -------------------------------------------------------------- tiled GEMM
// 128 x BN tiles, K-step 64, gload_lds staging (lane-linear LDS dest,
// XOR-swizzled per-lane global source), single-buffer 2-barrier (m97).
// MODE 0 (BN=128): out -> Q/K f16 [B][H][N][D], V TRANSPOSED [B][H][D][N];
//                  + bias; Q scaled by QSCALE.  grid (64, 12).
// MODE 1 (BN=64):  out -> float [M][512] + bias.  grid (64, 8).
template <int BN, int MODE>
__global__ __launch_bounds__(256) void k_gemm(
    const f16* __restrict__ A, const f16* __restrict__ Wb3,
    const float* __restrict__ bias0, const float* __restrict__ bias1,
    const float* __restrict__ bias2, f16* __restrict__ oQ, f16* __restrict__ oK,
    f16* __restrict__ oV, float* __restrict__ oOut) {
  __shared__ __align__(16) f16 a_lds[128 * 64];
  __shared__ __align__(16) f16 b_lds[BN * 64];
  const int t = threadIdx.x;
  const int lane = t & 63, wid = t >> 6;
  const int l15 = lane & 15, l4 = lane >> 4;
  constexpr int MT = (BN == 128) ? 4 : 2;
  const int mbase = (BN == 128) ? (wid >> 1) * 64 : wid * 32;
  const int nbase = (BN == 128) ? (wid & 1) * 64 : 0;
  const int m0 = blockIdx.x * 128;
  const int by = blockIdx.y;
  const int wsel = (MODE == 0) ? (by >> 2) : 0;
  const int n0l = (MODE == 0) ? ((by & 3) * 128) : (by * (BN == 64 ? 64 : 128));
  const f16* Wt = Wb3 + (size_t)wsel * 262144;

  const int srow = t >> 3;                    // 0..31
  const int sswz = ((t & 7) ^ (srow & 7)) * 8;  // swizzled k-offset
  const f16* Ag = A + (size_t)(m0 + srow) * 512 + sswz;
  const f16* Bg = Wt + (size_t)(n0l + srow) * 512 + sswz;

  f32x4 acc[MT][4];
  const f32x4 z4 = {0.f, 0.f, 0.f, 0.f};
#pragma unroll
  for (int i = 0; i < MT; i++)
#pragma unroll
    for (int j = 0; j < 4; j++) acc[i][j] = z4;

  for (int k0 = 0; k0 < 512; k0 += 64) {
#pragma unroll
    for (int i = 0; i < 4; i++)
      GLLDS16(Ag + (size_t)i * 16384 + k0, &a_lds[i * 2048 + wid * 512]);
#pragma unroll
    for (int i = 0; i < BN / 32; i++)
      GLLDS16(Bg + (size_t)i * 16384 + k0, &b_lds[i * 2048 + wid * 512]);
    __syncthreads();
#pragma unroll
    for (int ks = 0; ks < 2; ks++) {
      const int rs = ((ks * 4 + l4) ^ (l15 & 7)) * 8;
      f16x8 af[MT], bf[4];
#pragma unroll
      for (int mt = 0; mt < MT; mt++)
        af[mt] = *(const f16x8*)&a_lds[(mbase + mt * 16 + l15) * 64 + rs];
#pragma unroll
      for (int nt = 0; nt < 4; nt++)
        bf[nt] = *(const f16x8*)&b_lds[(nbase + nt * 16 + l15) * 64 + rs];
      __builtin_amdgcn_s_setprio(1);
#pragma unroll
      for (int mt = 0; mt < MT; mt++)
#pragma unroll
        for (int nt = 0; nt < 4; nt++)
          acc[mt][nt] = MFMA16(af[mt], bf[nt], acc[mt][nt]);
      __builtin_amdgcn_s_setprio(0);
    }
    __syncthreads();
  }

  if (MODE == 1) {
#pragma unroll
    for (int mt = 0; mt < MT; mt++)
#pragma unroll
      for (int nt = 0; nt < 4; nt++) {
        const int row = m0 + mbase + mt * 16 + l4 * 4;
        const int col = n0l + nbase + nt * 16 + l15;
        const float bv = bias0[col];
#pragma unroll
        for (int r = 0; r < 4; r++)
          oOut[(size_t)(row + r) * 512 + col] = acc[mt][nt][r] + bv;
      }
  } else {
#pragma unroll
    for (int mt = 0; mt < MT; mt++)
#pragma unroll
      for (int nt = 0; nt < 4; nt++) {
        const int colg = by * 128 + nbase + nt * 16 + l15;
        const int w = colg >> 9, jj = colg & 511;
        const int h = jj >> 6, d = jj & 63;
        const float* bp = (w == 0) ? bias0 : (w == 1) ? bias1 : bias2;
        const float bv = bp[jj];
        const float scl = (w == 0) ? QSCALE : 1.0f;  // fold softmax scale into Q
        const int rowg = m0 + mbase + mt * 16 + l4 * 4;
        const int b = rowg >> 11, nn = rowg & 2047;
        if (w == 2) {
          // V transposed: Vt[((b*8+h)*64 + d)*2048 + n]
          const size_t vb = ((size_t)(b * 8 + h) * 64 + d) * 2048 + nn;
#pragma unroll
          for (int r = 0; r < 4; r++)
            oV[vb + r] = (f16)(acc[mt][nt][r] + bv);
        } else {
          f16* op = (w == 0) ? oQ : oK;
          const size_t base = ((size_t)(b * 8 + h) * 2048 + nn) * 64 + d;
#pragma unroll
          for (int r = 0; r < 4; r++)
            op[base + (size_t)r * 64] = (f16)((acc[mt][nt][r] + bv) * scl);
        }
      }
  }
}

// ---------------------------------------------------------- flash attention
// grid: 1024 blocks: bits[2:0]=XCD, [7:3]=q-block(32), [9:8]=head-in-XCD.
// 128 threads = 2 waves x 32 q-rows (2 q-sets of 16) -> 4 blocks/CU.
// KV tiles of 64, dbuf, 1 barrier/tile, staging via global_load_lds.
// K staged with row-permutation pi + XOR swizzle; Vt staged [64d][64kv].
// Swapped QK^T; P = exp2(st) in-register -> K32 PV A-frags by pure concat.
__global__ __launch_bounds__(128, 4) void k_attn(const f16* __restrict__ Q,
                                                 const f16* __restrict__ K,
                                                 const f16* __restrict__ Vt,
                                                 f16* __restrict__ CTX) {
  __shared__ __align__(16) f16 k_lds[2][4096];
  __shared__ __align__(16) f16 v_lds[2][4096];
  const int t = threadIdx.x, wid = t >> 6, lane = t & 63;
  const int l15 = lane & 15, l4 = lane >> 4;
  const int bid = blockIdx.x;
  const int bh = (bid & 7) * 4 + (bid >> 8);
  const int qb = (bid >> 3) & 31;
  const int q0 = qb * 64 + wid * 32;
  const size_t kvb = (size_t)bh * (2048 * 64);

  // Q fragments (B-operand of swapped QK^T), 2 q-sets
  f16x8 qf[2][2];
#pragma unroll
  for (int g = 0; g < 2; g++)
#pragma unroll
    for (int ks = 0; ks < 2; ks++)
      qf[g][ks] = *(const f16x8*)&Q[kvb + (size_t)(q0 + g * 16 + l15) * 64 +
                                    ks * 32 + l4 * 8];

  f32x4 oa[2][4];
  f32x4 lacc[2];
  const f32x4 z4 = {0.f, 0.f, 0.f, 0.f};
#pragma unroll
  for (int g = 0; g < 2; g++) {
    lacc[g] = z4;
#pragma unroll
    for (int dt = 0; dt < 4; dt++) oa[g][dt] = z4;
  }
  const f16 one = (f16)1.0f;
  const f16x8 ones = {one, one, one, one, one, one, one, one};

  // staging: 4 issues x (K,V); LDS elem = i*1024 + wid*512 + lane*8.
  // logical row L = i*16 + wid*8 + (lane>>3); K stages physical row pi(L):
  // pi = bit5 | bits3:2<<1 | bit4>>2 | bits1:0.  V stages physical row L.
  const int kswz = ((lane & 7) ^ (lane >> 3)) * 8;
  const f16* Kgp[4];
  const f16* Vgp[4];
#pragma unroll
  for (int i = 0; i < 4; i++) {
    const int L = i * 16 + wid * 8 + (lane >> 3);
    const int pr = (L & 0x20) | ((L & 0x0C) << 1) | ((L & 0x10) >> 2) | (L & 3);
    Kgp[i] = K + kvb + (size_t)pr * 64 + kswz;
    Vgp[i] = Vt + kvb + (size_t)L * 2048 + kswz;
  }

  // ---- prologue: stage tile 0 into buffer 0
#pragma unroll
  for (int i = 0; i < 4; i++) {
    GLLDS16(Kgp[i], &k_lds[0][i * 1024 + wid * 512]);
    GLLDS16(Vgp[i], &v_lds[0][i * 1024 + wid * 512]);
  }
  __syncthreads();

  int cur = 0;
  for (int it = 0; it < 32; ++it) {
    if (it < 31) {
      const size_t kb = (size_t)(it + 1) * 4096;  // K advances 64 rows
      const size_t vb = (size_t)(it + 1) * 64;    // Vt advances 64 cols
#pragma unroll
      for (int i = 0; i < 4; i++) {
        GLLDS16(Kgp[i] + kb, &k_lds[cur ^ 1][i * 1024 + wid * 512]);
        GLLDS16(Vgp[i] + vb, &v_lds[cur ^ 1][i * 1024 + wid * 512]);
      }
    }

    // ---- S^T = K Q^T: lane holds st[g][w][r] = S[q=l15][kv_log=w*16+l4*4+r]
    f32x4 st[2][4];
#pragma unroll
    for (int g = 0; g < 2; g++)
#pragma unroll
      for (int w = 0; w < 4; w++) st[g][w] = z4;
    const f16* kl = k_lds[cur];
#pragma unroll
    for (int ks = 0; ks < 2; ks++) {
      const int rs = ((ks * 4 + l4) ^ (l15 & 7)) * 8;
      f16x8 kf[4];
#pragma unroll
      for (int w = 0; w < 4; w++)
        kf[w] = *(const f16x8*)&kl[(w * 16 + l15) * 64 + rs];
      __builtin_amdgcn_s_setprio(1);
#pragma unroll
      for (int w = 0; w < 4; w++) {
        st[0][w] = MFMA16(kf[w], qf[0][ks], st[0][w]);
        st[1][w] = MFMA16(kf[w], qf[1][ks], st[1][w]);
      }
      __builtin_amdgcn_s_setprio(0);
    }

    // ---- P = exp2(st) packed straight into K32 PV A-frags (pi-aligned)
    f16x8 pa[2][2];
#pragma unroll
    for (int g = 0; g < 2; g++)
#pragma unroll
      for (int ks = 0; ks < 2; ks++) {
        f16x2 a0 = __builtin_bit_cast(
            f16x2, __builtin_amdgcn_cvt_pkrtz(EXP2(st[g][2 * ks][0]),
                                              EXP2(st[g][2 * ks][1])));
        f16x2 a1 = __builtin_bit_cast(
            f16x2, __builtin_amdgcn_cvt_pkrtz(EXP2(st[g][2 * ks][2]),
                                              EXP2(st[g][2 * ks][3])));
        f16x2 a2 = __builtin_bit_cast(
            f16x2, __builtin_amdgcn_cvt_pkrtz(EXP2(st[g][2 * ks + 1][0]),
                                              EXP2(st[g][2 * ks + 1][1])));
        f16x2 a3 = __builtin_bit_cast(
            f16x2, __builtin_amdgcn_cvt_pkrtz(EXP2(st[g][2 * ks + 1][2]),
                                              EXP2(st[g][2 * ks + 1][3])));
        f16x8 p;
        p[0] = a0[0]; p[1] = a0[1]; p[2] = a1[0]; p[3] = a1[1];
        p[4] = a2[0]; p[5] = a2[1]; p[6] = a3[0]; p[7] = a3[1];
        pa[g][ks] = p;
      }

    // ---- O += P V (K32), l += P 1 (ones-MFMA); vf shared across q-sets
    const f16* vl = v_lds[cur];
#pragma unroll
    for (int ks = 0; ks < 2; ks++) {
      __builtin_amdgcn_s_setprio(1);
      lacc[0] = MFMA16(pa[0][ks], ones, lacc[0]);
      lacc[1] = MFMA16(pa[1][ks], ones, lacc[1]);
#pragma unroll
      for (int dt = 0; dt < 4; dt++) {
        const f16x8 vf = *(const f16x8*)&vl[(dt * 16 + l15) * 64 +
                                            ((ks * 4 + l4) ^ (l15 & 7)) * 8];
        oa[0][dt] = MFMA16(pa[0][ks], vf, oa[0][dt]);
        oa[1][dt] = MFMA16(pa[1][ks], vf, oa[1][dt]);
      }
      __builtin_amdgcn_s_setprio(0);
    }
    __syncthreads();
    cur ^= 1;
  }

  // ---- epilogue: O /= l (both in C-layout: q = q0 + g*16 + l4*4 + r)
  const int b = bh >> 3, h = bh & 7;
#pragma unroll
  for (int g = 0; g < 2; g++)
#pragma unroll
    for (int r = 0; r < 4; r++) {
      const float inv = 1.0f / lacc[g][r];
      const int qrow = q0 + g * 16 + l4 * 4 + r;
#pragma unroll
      for (int dt = 0; dt < 4; dt++)
        CTX[(size_t)(b * 2048 + qrow) * 512 + h * 64 + dt * 16 + l15] =
            (f16)(oa[g][dt][r] * inv);
    }
}

// ----------------------------------------------------------------- launcher
extern "C" void kernel_launch(void* const* d_in, const int* in_sizes, int n_in,
                              void* d_out, int out_size, void* d_ws,
                              size_t ws_size, hipStream_t stream) {
  const float* x = (const float*)d_in[0];
  const float* Wq = (const float*)d_in[1];
  const float* bq = (const float*)d_in[2];
  const float* Wk = (const float*)d_in[3];
  const float* bk = (const float*)d_in[4];
  const float* Wv = (const float*)d_in[5];
  const float* bv = (const float*)d_in[6];
  const float* Wo = (const float*)d_in[7];
  const float* bo = (const float*)d_in[8];
  float* out = (float*)d_out;
  char* ws = (char*)d_ws;

  f16* xb = (f16*)(ws);                        // 8 MB
  f16* wt = (f16*)(ws + (size_t)(8u << 20));   // 2 MB  [4][512][512]
  f16* Qb = (f16*)(ws + (size_t)(10u << 20));  // 8 MB  [B][H][N][D]
  f16* Kb = (f16*)(ws + (size_t)(18u << 20));  // 8 MB  [B][H][N][D]
  f16* Vt = (f16*)(ws + (size_t)(26u << 20));  // 8 MB  [B][H][D][N]
  f16* CX = (f16*)(ws + (size_t)(34u << 20));  // 8 MB  [B][N][F]

  k_cvt_x<<<dim3(2048), dim3(256), 0, stream>>>(x, xb, 1048576);
  k_cvt_w<<<dim3(256, 4), dim3(256), 0, stream>>>(Wq, Wk, Wv, Wo, wt);
  k_gemm<128, 0><<<dim3(64, 12), dim3(256), 0, stream>>>(
      xb, wt, bq, bk, bv, Qb, Kb, Vt, nullptr);
  k_attn<<<dim3(1024), dim3(128), 0, stream>>>(Qb, Kb, Vt, CX);
  k_gemm<64, 1><<<dim3(64, 8), dim3(256), 0, stream>>>(
      CX, wt + (size_t)3 * 262144, bo, nullptr, nullptr, nullptr, nullptr,
      nullptr, out);
}

// Round 8
// 84.661 us; speedup vs baseline: 1.1452x; 1.1452x over previous
//
#include <hip/hip_runtime.h>

// MultiHeadSelfAttention: B=4 N=2048 F=512 H=8 D=64, scale = 1/sqrt(512)
// Pipeline: cvt x->f16, cvt W^T->f16, fused QKV GEMM (mfma f16, gload_lds
// staging, Q pre-scaled by log2e/sqrt(512), V stored TRANSPOSED [B][H][D][N]),
// flash attention (swapped QK^T + K-row permutation pi, no-max softmax,
// ones-MFMA denominators, TRIPLE-buffered KV with counted vmcnt + raw
// s_barrier -- no vmcnt(0) drain in the main loop), output GEMM (128x64,
// fp32+bias).
// ws: xb@0 | wt@8MB | Q@10MB K@18MB Vt@26MB | CTX@34MB.

typedef _Float16 f16;
typedef _Float16 f16x2 __attribute__((ext_vector_type(2)));
typedef _Float16 f16x4 __attribute__((ext_vector_type(4)));
typedef _Float16 f16x8 __attribute__((ext_vector_type(8)));
typedef float f32x4 __attribute__((ext_vector_type(4)));

#define MFMA16(a, b, c) __builtin_amdgcn_mfma_f32_16x16x32_f16((a), (b), (c), 0, 0, 0)
#if __has_builtin(__builtin_amdgcn_exp2f)
#define EXP2(x) __builtin_amdgcn_exp2f(x)
#else
#define EXP2(x) exp2f(x)
#endif
#define GLLDS16(gp, lp)                                                    \
  __builtin_amdgcn_global_load_lds(                                        \
      (const __attribute__((address_space(1))) unsigned int*)(gp),         \
      (__attribute__((address_space(3))) unsigned int*)(lp), 16, 0, 0)

// log2(e) / sqrt(512)
#define QSCALE 0.0637587f

// ---------------------------------------------------------------- cvt x -> f16
__global__ __launch_bounds__(256) void k_cvt_x(const float* __restrict__ x,
                                               f16* __restrict__ xb, int n4) {
  int i = blockIdx.x * 256 + threadIdx.x;
  const int stride = gridDim.x * 256;
  const float4* xp = (const float4*)x;
  f16x4* op = (f16x4*)xb;
  for (; i < n4; i += stride) {
    float4 v = xp[i];
    f16x4 o = {(f16)v.x, (f16)v.y, (f16)v.z, (f16)v.w};
    op[i] = o;
  }
}

// ------------------------------------------------- cvt weights -> W^T in f16
__global__ __launch_bounds__(256) void k_cvt_w(const float* __restrict__ Wq,
                                               const float* __restrict__ Wk,
                                               const float* __restrict__ Wv,
                                               const float* __restrict__ Wo,
                                               f16* __restrict__ wt) {
  const int w = blockIdx.y;
  const float* W = (w == 0) ? Wq : (w == 1) ? Wk : (w == 2) ? Wv : Wo;
  const int j0 = (blockIdx.x >> 4) * 32;
  const int k0 = (blockIdx.x & 15) * 32;
  __shared__ float tl[32][33];
  const int tx = threadIdx.x & 31, ty = threadIdx.x >> 5;
#pragma unroll
  for (int i = 0; i < 32; i += 8)
    tl[ty + i][tx] = W[(size_t)(k0 + ty + i) * 512 + j0 + tx];
  __syncthreads();
#pragma unroll
  for (int i = 0; i < 32; i += 8)
    wt[(size_t)w * 262144 + (size_t)(j0 + ty + i) * 512 + (k0 + tx)] =
        (f16)tl[tx][ty + i];
}

// -------------------------------------------------------------- tiled GEMM
// 128 x BN tiles, K-step 64, gload_lds staging (lane-linear LDS dest,
// XOR-swizzled per-lane global source), single-buffer 2-barrier (m97).
// MODE 0 (BN=128): out -> Q/K f16 [B][H][N][D], V TRANSPOSED [B][H][D][N];
//                  + bias; Q scaled by QSCALE.  grid (64, 12).
// MODE 1 (BN=64):  out -> float [M][512] + bias.  grid (64, 8).
template <int BN, int MODE>
__global__ __launch_bounds__(256) void k_gemm(
    const f16* __restrict__ A, const f16* __restrict__ Wb3,
    const float* __restrict__ bias0, const float* __restrict__ bias1,
    const float* __restrict__ bias2, f16* __restrict__ oQ, f16* __restrict__ oK,
    f16* __restrict__ oV, float* __restrict__ oOut) {
  __shared__ __align__(16) f16 a_lds[128 * 64];
  __shared__ __align__(16) f16 b_lds[BN * 64];
  const int t = threadIdx.x;
  const int lane = t & 63, wid = t >> 6;
  const int l15 = lane & 15, l4 = lane >> 4;
  constexpr int MT = (BN == 128) ? 4 : 2;
  const int mbase = (BN == 128) ? (wid >> 1) * 64 : wid * 32;
  const int nbase = (BN == 128) ? (wid & 1) * 64 : 0;
  const int m0 = blockIdx.x * 128;
  const int by = blockIdx.y;
  const int wsel = (MODE == 0) ? (by >> 2) : 0;
  const int n0l = (MODE == 0) ? ((by & 3) * 128) : (by * (BN == 64 ? 64 : 128));
  const f16* Wt = Wb3 + (size_t)wsel * 262144;

  const int srow = t >> 3;                      // 0..31
  const int sswz = ((t & 7) ^ (srow & 7)) * 8;  // swizzled k-offset
  const f16* Ag = A + (size_t)(m0 + srow) * 512 + sswz;
  const f16* Bg = Wt + (size_t)(n0l + srow) * 512 + sswz;

  f32x4 acc[MT][4];
  const f32x4 z4 = {0.f, 0.f, 0.f, 0.f};
#pragma unroll
  for (int i = 0; i < MT; i++)
#pragma unroll
    for (int j = 0; j < 4; j++) acc[i][j] = z4;

  for (int k0 = 0; k0 < 512; k0 += 64) {
#pragma unroll
    for (int i = 0; i < 4; i++)
      GLLDS16(Ag + (size_t)i * 16384 + k0, &a_lds[i * 2048 + wid * 512]);
#pragma unroll
    for (int i = 0; i < BN / 32; i++)
      GLLDS16(Bg + (size_t)i * 16384 + k0, &b_lds[i * 2048 + wid * 512]);
    __syncthreads();
#pragma unroll
    for (int ks = 0; ks < 2; ks++) {
      const int rs = ((ks * 4 + l4) ^ (l15 & 7)) * 8;
      f16x8 af[MT], bf[4];
#pragma unroll
      for (int mt = 0; mt < MT; mt++)
        af[mt] = *(const f16x8*)&a_lds[(mbase + mt * 16 + l15) * 64 + rs];
#pragma unroll
      for (int nt = 0; nt < 4; nt++)
        bf[nt] = *(const f16x8*)&b_lds[(nbase + nt * 16 + l15) * 64 + rs];
      __builtin_amdgcn_s_setprio(1);
#pragma unroll
      for (int mt = 0; mt < MT; mt++)
#pragma unroll
        for (int nt = 0; nt < 4; nt++)
          acc[mt][nt] = MFMA16(af[mt], bf[nt], acc[mt][nt]);
      __builtin_amdgcn_s_setprio(0);
    }
    __syncthreads();
  }

  if (MODE == 1) {
#pragma unroll
    for (int mt = 0; mt < MT; mt++)
#pragma unroll
      for (int nt = 0; nt < 4; nt++) {
        const int row = m0 + mbase + mt * 16 + l4 * 4;
        const int col = n0l + nbase + nt * 16 + l15;
        const float bv = bias0[col];
#pragma unroll
        for (int r = 0; r < 4; r++)
          oOut[(size_t)(row + r) * 512 + col] = acc[mt][nt][r] + bv;
      }
  } else {
#pragma unroll
    for (int mt = 0; mt < MT; mt++)
#pragma unroll
      for (int nt = 0; nt < 4; nt++) {
        const int colg = by * 128 + nbase + nt * 16 + l15;
        const int w = colg >> 9, jj = colg & 511;
        const int h = jj >> 6, d = jj & 63;
        const float* bp = (w == 0) ? bias0 : (w == 1) ? bias1 : bias2;
        const float bv = bp[jj];
        const float scl = (w == 0) ? QSCALE : 1.0f;  // fold softmax scale into Q
        const int rowg = m0 + mbase + mt * 16 + l4 * 4;
        const int b = rowg >> 11, nn = rowg & 2047;
        if (w == 2) {
          // V transposed: Vt[((b*8+h)*64 + d)*2048 + n]
          const size_t vb = ((size_t)(b * 8 + h) * 64 + d) * 2048 + nn;
#pragma unroll
          for (int r = 0; r < 4; r++)
            oV[vb + r] = (f16)(acc[mt][nt][r] + bv);
        } else {
          f16* op = (w == 0) ? oQ : oK;
          const size_t base = ((size_t)(b * 8 + h) * 2048 + nn) * 64 + d;
#pragma unroll
          for (int r = 0; r < 4; r++)
            op[base + (size_t)r * 64] = (f16)((acc[mt][nt][r] + bv) * scl);
        }
      }
  }
}

// ---------------------------------------------------------- flash attention
// grid: 512 blocks: bits[2:0]=XCD, [6:3]=q-block(16), [8:7]=head-in-XCD.
// 4 waves x 32 q-rows (2 q-sets of 16). KV tiles of 64.
// TRIPLE-buffered LDS (48KB), 2-deep prefetch, counted s_waitcnt vmcnt(4)
// + raw s_barrier per tile (loads stay in flight across barriers; no drain).
// K staged with row-permutation pi + XOR swizzle; Vt staged [64d][64kv].
// Swapped QK^T; P = exp2(st) in-register -> K32 PV A-frags by pure concat.
__global__ __launch_bounds__(256, 2) void k_attn(const f16* __restrict__ Q,
                                                 const f16* __restrict__ K,
                                                 const f16* __restrict__ Vt,
                                                 f16* __restrict__ CTX) {
  __shared__ __align__(16) f16 k_lds[3][4096];
  __shared__ __align__(16) f16 v_lds[3][4096];
  const int t = threadIdx.x, wid = t >> 6, lane = t & 63;
  const int l15 = lane & 15, l4 = lane >> 4;
  const int bid = blockIdx.x;
  const int bh = (bid & 7) * 4 + (bid >> 7);
  const int qb = (bid >> 3) & 15;
  const int q0 = qb * 128 + wid * 32;
  const size_t kvb = (size_t)bh * (2048 * 64);

  // Q fragments (B-operand of swapped QK^T), 2 q-sets
  f16x8 qf[2][2];
#pragma unroll
  for (int g = 0; g < 2; g++)
#pragma unroll
    for (int ks = 0; ks < 2; ks++)
      qf[g][ks] = *(const f16x8*)&Q[kvb + (size_t)(q0 + g * 16 + l15) * 64 +
                                    ks * 32 + l4 * 8];

  f32x4 oa[2][4];
  f32x4 lacc[2];
  const f32x4 z4 = {0.f, 0.f, 0.f, 0.f};
#pragma unroll
  for (int g = 0; g < 2; g++) {
    lacc[g] = z4;
#pragma unroll
    for (int dt = 0; dt < 4; dt++) oa[g][dt] = z4;
  }
  const f16 one = (f16)1.0f;
  const f16x8 ones = {one, one, one, one, one, one, one, one};

  // staging geometry: LDS elem E = issue*2048 + wid*512 + lane*8
  // K: logical row L = issue*32 + krow; stage physical row pi(L); pi passes
  //    bit5 through, so issue 1 (+2048) is pi-consistent.
  const int krow = wid * 8 + (lane >> 3);
  const int kswz = ((lane & 7) ^ (lane >> 3)) * 8;
  const int kperm = ((krow & 0x0C) << 1) | ((krow & 0x10) >> 2) | (krow & 3);
  const f16* Kg = K + kvb + (size_t)kperm * 64 + kswz;
  const f16* Vg = Vt + kvb + (size_t)krow * 2048 + kswz;

  // ---- prologue: stage tiles 0 and 1 into buffers 0 and 1
#pragma unroll
  for (int p = 0; p < 2; p++) {
    GLLDS16(Kg + p * 4096, &k_lds[p][wid * 512]);
    GLLDS16(Kg + p * 4096 + 2048, &k_lds[p][wid * 512 + 2048]);
    GLLDS16(Vg + p * 64, &v_lds[p][wid * 512]);
    GLLDS16(Vg + p * 64 + 32 * 2048, &v_lds[p][wid * 512 + 2048]);
  }
  __syncthreads();

  int cur = 0, stg = 2;
  for (int it = 0; it < 32; ++it) {
    // stage tile it+2 into the buffer freed at the end of iteration it-1
    if (it < 30) {
      const size_t kb = (size_t)(it + 2) * 4096;  // K advances 64 rows
      const size_t vb = (size_t)(it + 2) * 64;    // Vt advances 64 cols
      GLLDS16(Kg + kb, &k_lds[stg][wid * 512]);
      GLLDS16(Kg + kb + 2048, &k_lds[stg][wid * 512 + 2048]);
      GLLDS16(Vg + vb, &v_lds[stg][wid * 512]);
      GLLDS16(Vg + vb + 32 * 2048, &v_lds[stg][wid * 512 + 2048]);
    }

    // ---- S^T = K Q^T: lane holds st[g][w][r] = S[q=l15][kv_log=w*16+l4*4+r]
    f32x4 st[2][4];
#pragma unroll
    for (int g = 0; g < 2; g++)
#pragma unroll
      for (int w = 0; w < 4; w++) st[g][w] = z4;
    const f16* kl = &k_lds[cur][0];
#pragma unroll
    for (int ks = 0; ks < 2; ks++) {
      const int rs = ((ks * 4 + l4) ^ (l15 & 7)) * 8;
      f16x8 kf[4];
#pragma unroll
      for (int w = 0; w < 4; w++)
        kf[w] = *(const f16x8*)&kl[(w * 16 + l15) * 64 + rs];
      __builtin_amdgcn_s_setprio(1);
#pragma unroll
      for (int w = 0; w < 4; w++) {
        st[0][w] = MFMA16(kf[w], qf[0][ks], st[0][w]);
        st[1][w] = MFMA16(kf[w], qf[1][ks], st[1][w]);
      }
      __builtin_amdgcn_s_setprio(0);
    }

    // ---- P = exp2(st) packed straight into K32 PV A-frags (pi-aligned)
    f16x8 pa[2][2];
#pragma unroll
    for (int g = 0; g < 2; g++)
#pragma unroll
      for (int ks = 0; ks < 2; ks++) {
        f16x2 a0 = __builtin_bit_cast(
            f16x2, __builtin_amdgcn_cvt_pkrtz(EXP2(st[g][2 * ks][0]),
                                              EXP2(st[g][2 * ks][1])));
        f16x2 a1 = __builtin_bit_cast(
            f16x2, __builtin_amdgcn_cvt_pkrtz(EXP2(st[g][2 * ks][2]),
                                              EXP2(st[g][2 * ks][3])));
        f16x2 a2 = __builtin_bit_cast(
            f16x2, __builtin_amdgcn_cvt_pkrtz(EXP2(st[g][2 * ks + 1][0]),
                                              EXP2(st[g][2 * ks + 1][1])));
        f16x2 a3 = __builtin_bit_cast(
            f16x2, __builtin_amdgcn_cvt_pkrtz(EXP2(st[g][2 * ks + 1][2]),
                                              EXP2(st[g][2 * ks + 1][3])));
        f16x8 p;
        p[0] = a0[0]; p[1] = a0[1]; p[2] = a1[0]; p[3] = a1[1];
        p[4] = a2[0]; p[5] = a2[1]; p[6] = a3[0]; p[7] = a3[1];
        pa[g][ks] = p;
      }

    // ---- O += P V (K32), l += P 1 (ones-MFMA); vf shared across q-sets
    const f16* vl = &v_lds[cur][0];
#pragma unroll
    for (int ks = 0; ks < 2; ks++) {
      __builtin_amdgcn_s_setprio(1);
      lacc[0] = MFMA16(pa[0][ks], ones, lacc[0]);
      lacc[1] = MFMA16(pa[1][ks], ones, lacc[1]);
#pragma unroll
      for (int dt = 0; dt < 4; dt++) {
        const f16x8 vf = *(const f16x8*)&vl[(dt * 16 + l15) * 64 +
                                            ((ks * 4 + l4) ^ (l15 & 7)) * 8];
        oa[0][dt] = MFMA16(pa[0][ks], vf, oa[0][dt]);
        oa[1][dt] = MFMA16(pa[1][ks], vf, oa[1][dt]);
      }
      __builtin_amdgcn_s_setprio(0);
    }

    // ---- counted wait + raw barrier: tile it+1's loads are landed; tile
    // it+2's 4 loads stay in flight across the barrier (no vmcnt(0) drain).
    if (it < 31) {
      if (it < 30)
        asm volatile("s_waitcnt vmcnt(4)" ::: "memory");
      else
        asm volatile("s_waitcnt vmcnt(0)" ::: "memory");
      __builtin_amdgcn_s_barrier();
      __builtin_amdgcn_sched_barrier(0);
    }
    cur = (cur == 2) ? 0 : cur + 1;
    stg = (stg == 2) ? 0 : stg + 1;
  }

  // ---- epilogue: O /= l (both in C-layout: q = q0 + g*16 + l4*4 + r)
  const int b = bh >> 3, h = bh & 7;
#pragma unroll
  for (int g = 0; g < 2; g++)
#pragma unroll
    for (int r = 0; r < 4; r++) {
      const float inv = 1.0f / lacc[g][r];
      const int qrow = q0 + g * 16 + l4 * 4 + r;
#pragma unroll
      for (int dt = 0; dt < 4; dt++)
        CTX[(size_t)(b * 2048 + qrow) * 512 + h * 64 + dt * 16 + l15] =
            (f16)(oa[g][dt][r] * inv);
    }
}

// ----------------------------------------------------------------- launcher
extern "C" void kernel_launch(void* const* d_in, const int* in_sizes, int n_in,
                              void* d_out, int out_size, void* d_ws,
                              size_t ws_size, hipStream_t stream) {
  const float* x = (const float*)d_in[0];
  const float* Wq = (const float*)d_in[1];
  const float* bq = (const float*)d_in[2];
  const float* Wk = (const float*)d_in[3];
  const float* bk = (const float*)d_in[4];
  const float* Wv = (const float*)d_in[5];
  const float* bv = (const float*)d_in[6];
  const float* Wo = (const float*)d_in[7];
  const float* bo = (const float*)d_in[8];
  float* out = (float*)d_out;
  char* ws = (char*)d_ws;

  f16* xb = (f16*)(ws);                        // 8 MB
  f16* wt = (f16*)(ws + (size_t)(8u << 20));   // 2 MB  [4][512][512]
  f16* Qb = (f16*)(ws + (size_t)(10u << 20));  // 8 MB  [B][H][N][D]
  f16* Kb = (f16*)(ws + (size_t)(18u << 20));  // 8 MB  [B][H][N][D]
  f16* Vt = (f16*)(ws + (size_t)(26u << 20));  // 8 MB  [B][H][D][N]
  f16* CX = (f16*)(ws + (size_t)(34u << 20));  // 8 MB  [B][N][F]

  k_cvt_x<<<dim3(2048), dim3(256), 0, stream>>>(x, xb, 1048576);
  k_cvt_w<<<dim3(256, 4), dim3(256), 0, stream>>>(Wq, Wk, Wv, Wo, wt);
  k_gemm<128, 0><<<dim3(64, 12), dim3(256), 0, stream>>>(
      xb, wt, bq, bk, bv, Qb, Kb, Vt, nullptr);
  k_attn<<<dim3(512), dim3(256), 0, stream>>>(Qb, Kb, Vt, CX);
  k_gemm<64, 1><<<dim3(64, 8), dim3(256), 0, stream>>>(
      CX, wt + (size_t)3 * 262144, bo, nullptr, nullptr, nullptr, nullptr,
      nullptr, out);
}